// Round 4
// baseline (267.891 us; speedup 1.0000x reference)
//
#include <hip/hip_runtime.h>

#define D 128
#define NSEG 2048
#define EPSV 1e-6f
#define BLOCK 256
#define CPR 32           // float4 chunks per row (128/4)
#define RG (BLOCK/CPR)   // 8 row-groups
#define WAVES (BLOCK/64) // 4

typedef float f32x4 __attribute__((ext_vector_type(4)));

#define ACC(v, sum, sq) { (sum) += (v); (sq) += (v) * (v); }

// 4 waves/block, 8 blocks/CU -> whole 2048-block grid resident at once.
__global__ __launch_bounds__(BLOCK, 8) void graphnorm_fused(
    const float* __restrict__ feat,
    const int* __restrict__ seg,
    const float* __restrict__ weight,
    const float* __restrict__ bias,
    const float* __restrict__ mean_scale,
    float* __restrict__ out,
    int N)
{
    const int s = blockIdx.x;
    __shared__ int s_range[2];
    __shared__ f32x4 s_sum[WAVES][CPR];  // 2 KB
    __shared__ f32x4 s_sq[WAVES][CPR];   // 2 KB
    __shared__ f32x4 s_a[CPR];
    __shared__ f32x4 s_b[CPR];

    const int t = threadIdx.x;

    // lower_bound for segment s (thread 0) and s+1 (thread 1)
    if (t < 2) {
        int target = s + t;
        int lo = 0, hi = N;
        while (lo < hi) {
            int mid = (lo + hi) >> 1;
            if (seg[mid] < target) lo = mid + 1; else hi = mid;
        }
        s_range[t] = lo;
    }
    __syncthreads();
    const int start = s_range[0];
    const int end   = s_range[1];

    const int c = t & (CPR - 1);   // float4 column chunk 0..31
    const int g = t >> 5;          // row group 0..7

    const f32x4* feat4 = reinterpret_cast<const f32x4*>(feat);
    f32x4* out4 = reinterpret_cast<f32x4*>(out);

    // ---- pass 1: 4 independent loads in flight, 2 accumulator pairs ----
    f32x4 s0 = 0.f, s1 = 0.f;
    f32x4 q0 = 0.f, q1 = 0.f;

    int r = start + g;
    for (; r + 3 * RG < end; r += 4 * RG) {
        f32x4 v0 = feat4[(r         ) * CPR + c];
        f32x4 v1 = feat4[(r +     RG) * CPR + c];
        f32x4 v2 = feat4[(r + 2 * RG) * CPR + c];
        f32x4 v3 = feat4[(r + 3 * RG) * CPR + c];
        ACC(v0, s0, q0);
        ACC(v1, s1, q1);
        ACC(v2, s0, q0);
        ACC(v3, s1, q1);
    }
    for (; r < end; r += RG) {
        f32x4 v = feat4[r * CPR + c];
        ACC(v, s0, q0);
    }
    s0 += s1;
    q0 += q1;

    // wave-level reduce: lanes l and l^32 hold the same column chunk c
    #pragma unroll
    for (int i = 0; i < 4; ++i) {
        s0[i] += __shfl_xor(s0[i], 32);
        q0[i] += __shfl_xor(q0[i], 32);
    }

    const int w    = t >> 6;   // wave id 0..3
    const int lane = t & 63;
    if (lane < 32) {
        s_sum[w][c] = s0;
        s_sq[w][c]  = q0;
    }
    __syncthreads();

    // ---- per-column affine coefficients (threads 0..31) ----
    if (t < CPR) {
        f32x4 sm = s_sum[0][t];
        f32x4 sg = s_sq[0][t];
        #pragma unroll
        for (int i = 1; i < WAVES; ++i) {
            sm += s_sum[i][t];
            sg += s_sq[i][t];
        }
        const float cnt = (float)max(end - start, 1);
        const float inv = 1.0f / cnt;
        const f32x4 wv  = reinterpret_cast<const f32x4*>(weight)[t];
        const f32x4 bi  = reinterpret_cast<const f32x4*>(bias)[t];
        const f32x4 msc = reinterpret_cast<const f32x4*>(mean_scale)[t];
        f32x4 A, B;
        #pragma unroll
        for (int i = 0; i < 4; ++i) {
            float mean = sm[i] * inv;
            float ms   = mean * msc[i];
            float var  = fmaxf(sg[i] * inv - 2.f * mean * ms + ms * ms, 0.f);
            float istd = rsqrtf(var + EPSV);
            A[i] = wv[i] * istd;
            B[i] = bi[i] - A[i] * ms;
        }
        s_a[t] = A;
        s_b[t] = B;
    }
    __syncthreads();

    // ---- pass 2: apply out = a*x + b, reads are L2/L3 hits, nt stores ----
    const f32x4 A = s_a[c];
    const f32x4 B = s_b[c];

    r = start + g;
    for (; r + 3 * RG < end; r += 4 * RG) {
        const int i0 = (r         ) * CPR + c;
        const int i1 = (r +     RG) * CPR + c;
        const int i2 = (r + 2 * RG) * CPR + c;
        const int i3 = (r + 3 * RG) * CPR + c;
        f32x4 v0 = feat4[i0];
        f32x4 v1 = feat4[i1];
        f32x4 v2 = feat4[i2];
        f32x4 v3 = feat4[i3];
        __builtin_nontemporal_store(A * v0 + B, &out4[i0]);
        __builtin_nontemporal_store(A * v1 + B, &out4[i1]);
        __builtin_nontemporal_store(A * v2 + B, &out4[i2]);
        __builtin_nontemporal_store(A * v3 + B, &out4[i3]);
    }
    for (; r < end; r += RG) {
        const int idx = r * CPR + c;
        f32x4 v = feat4[idx];
        __builtin_nontemporal_store(A * v + B, &out4[idx]);
    }
}

extern "C" void kernel_launch(void* const* d_in, const int* in_sizes, int n_in,
                              void* d_out, int out_size, void* d_ws, size_t ws_size,
                              hipStream_t stream) {
    const float* feat       = (const float*)d_in[0];
    const int*   seg        = (const int*)d_in[1];
    const float* weight     = (const float*)d_in[2];
    const float* bias       = (const float*)d_in[3];
    const float* mean_scale = (const float*)d_in[4];
    float* out = (float*)d_out;

    const int N = in_sizes[0] / D;   // 1,000,000

    graphnorm_fused<<<NSEG, BLOCK, 0, stream>>>(
        feat, seg, weight, bias, mean_scale, out, N);
}

// Round 5
// 227.465 us; speedup vs baseline: 1.1777x; 1.1777x over previous
//
#include <hip/hip_runtime.h>

#define D 128
#define NSEG 2048
#define EPSV 1e-6f
#define BLOCK 512
#define CPR 32           // float4 chunks per row (128/4)
#define RG (BLOCK/CPR)   // 16 row-groups
#define WAVES (BLOCK/64) // 8
#define MAXK 32          // buffered row-slots per thread: MAXK*RG = 512 rows/segment

typedef float f32x4 __attribute__((ext_vector_type(4)));

// One block per CU (VGPR-bound): whole segment lives in registers between
// the stats pass and the apply pass -> feat is read from HBM exactly once.
__global__ __launch_bounds__(BLOCK, 2) void graphnorm_fused(
    const float* __restrict__ feat,
    const int* __restrict__ seg,
    const float* __restrict__ weight,
    const float* __restrict__ bias,
    const float* __restrict__ mean_scale,
    float* __restrict__ out,
    int N)
{
    const int s = blockIdx.x;
    __shared__ int s_range[2];
    __shared__ f32x4 s_sum[WAVES][CPR];  // 4 KB
    __shared__ f32x4 s_sq[WAVES][CPR];   // 4 KB
    __shared__ f32x4 s_a[CPR];
    __shared__ f32x4 s_b[CPR];

    const int t = threadIdx.x;

    // lower_bound for segment s (thread 0) and s+1 (thread 1)
    if (t < 2) {
        int target = s + t;
        int lo = 0, hi = N;
        while (lo < hi) {
            int mid = (lo + hi) >> 1;
            if (seg[mid] < target) lo = mid + 1; else hi = mid;
        }
        s_range[t] = lo;
    }
    __syncthreads();
    const int start = s_range[0];
    const int end   = s_range[1];

    const int c = t & (CPR - 1);   // float4 column chunk 0..31
    const int g = t >> 5;          // row group 0..15

    const f32x4* feat4 = reinterpret_cast<const f32x4*>(feat);
    f32x4* out4 = reinterpret_cast<f32x4*>(out);

    // ---- pass 1a: bulk load into registers (statically indexed, unrolled) ----
    f32x4 buf[MAXK];
    #pragma unroll
    for (int k = 0; k < MAXK; ++k) {
        const int r = start + g + k * RG;
        if (r < end) buf[k] = feat4[r * CPR + c];
    }

    // ---- pass 1b: accumulate sum / sumsq from registers ----
    f32x4 s0 = 0.f, q0 = 0.f;
    #pragma unroll
    for (int k = 0; k < MAXK; ++k) {
        const int r = start + g + k * RG;
        if (r < end) {
            s0 += buf[k];
            q0 += buf[k] * buf[k];
        }
    }

    // tail rows beyond the register window (rare): accumulate via L2/L3
    const int tail_base = start + g + MAXK * RG;
    for (int r = tail_base; r < end; r += RG) {
        f32x4 v = feat4[r * CPR + c];
        s0 += v;
        q0 += v * v;
    }

    // wave-level reduce: lanes l and l^32 hold the same column chunk c
    #pragma unroll
    for (int i = 0; i < 4; ++i) {
        s0[i] += __shfl_xor(s0[i], 32);
        q0[i] += __shfl_xor(q0[i], 32);
    }

    const int w    = t >> 6;   // wave id 0..7
    const int lane = t & 63;
    if (lane < 32) {
        s_sum[w][c] = s0;
        s_sq[w][c]  = q0;
    }
    __syncthreads();

    // ---- per-column affine coefficients (threads 0..31) ----
    if (t < CPR) {
        f32x4 sm = s_sum[0][t];
        f32x4 sg = s_sq[0][t];
        #pragma unroll
        for (int i = 1; i < WAVES; ++i) {
            sm += s_sum[i][t];
            sg += s_sq[i][t];
        }
        const float cnt = (float)max(end - start, 1);
        const float inv = 1.0f / cnt;
        const f32x4 wv  = reinterpret_cast<const f32x4*>(weight)[t];
        const f32x4 bi  = reinterpret_cast<const f32x4*>(bias)[t];
        const f32x4 msc = reinterpret_cast<const f32x4*>(mean_scale)[t];
        f32x4 A, B;
        #pragma unroll
        for (int i = 0; i < 4; ++i) {
            float mean = sm[i] * inv;
            float ms   = mean * msc[i];
            float var  = fmaxf(sg[i] * inv - 2.f * mean * ms + ms * ms, 0.f);
            float istd = rsqrtf(var + EPSV);
            A[i] = wv[i] * istd;
            B[i] = bi[i] - A[i] * ms;
        }
        s_a[t] = A;
        s_b[t] = B;
    }
    __syncthreads();

    // ---- pass 2: apply from registers, zero loads, nontemporal stores ----
    const f32x4 A = s_a[c];
    const f32x4 B = s_b[c];

    #pragma unroll
    for (int k = 0; k < MAXK; ++k) {
        const int r = start + g + k * RG;
        if (r < end)
            __builtin_nontemporal_store(A * buf[k] + B, &out4[r * CPR + c]);
    }
    // tail rows: re-read via L2/L3
    for (int r = tail_base; r < end; r += RG) {
        f32x4 v = feat4[r * CPR + c];
        __builtin_nontemporal_store(A * v + B, &out4[r * CPR + c]);
    }
}

extern "C" void kernel_launch(void* const* d_in, const int* in_sizes, int n_in,
                              void* d_out, int out_size, void* d_ws, size_t ws_size,
                              hipStream_t stream) {
    const float* feat       = (const float*)d_in[0];
    const int*   seg        = (const int*)d_in[1];
    const float* weight     = (const float*)d_in[2];
    const float* bias       = (const float*)d_in[3];
    const float* mean_scale = (const float*)d_in[4];
    float* out = (float*)d_out;

    const int N = in_sizes[0] / D;   // 1,000,000

    graphnorm_fused<<<NSEG, BLOCK, 0, stream>>>(
        feat, seg, weight, bias, mean_scale, out, N);
}

// Round 6
// 200.135 us; speedup vs baseline: 1.3386x; 1.1366x over previous
//
#include <hip/hip_runtime.h>

#define D 128
#define NSEG 2048
#define EPSV 1e-6f
#define BLOCK 256
#define QCH 8            // f32x4 chunks per row owned by this block (32 columns)
#define CPRF 32          // f32x4 chunks per full row (128/4)
#define RG (BLOCK/QCH)   // 32 row-groups
#define WAVES (BLOCK/64) // 4
#define MAXK 16          // buffered slots/thread: MAXK*RG = 512 rows

typedef float f32x4 __attribute__((ext_vector_type(4)));

// Column-split: 4 blocks per segment (32 columns each). Per-column stats are
// independent -> no cross-block communication. buf[16]=64 VGPR -> <=128 total
// -> 4 blocks/CU resident, phases stagger so reads overlap writes.
__global__ __launch_bounds__(BLOCK, 4) void graphnorm_fused(
    const float* __restrict__ feat,
    const int* __restrict__ seg,
    const float* __restrict__ weight,
    const float* __restrict__ bias,
    const float* __restrict__ mean_scale,
    float* __restrict__ out,
    int N)
{
    const int bid = blockIdx.x;
    const int s = bid >> 2;        // segment
    const int q = bid & 3;         // column quarter
    __shared__ int s_range[2];
    __shared__ f32x4 s_sum[WAVES][QCH];
    __shared__ f32x4 s_sq[WAVES][QCH];
    __shared__ f32x4 s_a[QCH];
    __shared__ f32x4 s_b[QCH];

    const int t = threadIdx.x;

    // lower_bound for segment s (thread 0) and s+1 (thread 1)
    if (t < 2) {
        int target = s + t;
        int lo = 0, hi = N;
        while (lo < hi) {
            int mid = (lo + hi) >> 1;
            if (seg[mid] < target) lo = mid + 1; else hi = mid;
        }
        s_range[t] = lo;
    }
    __syncthreads();
    const int start = s_range[0];
    const int end   = s_range[1];

    const int c = t & (QCH - 1);       // chunk within this block's slice 0..7
    const int g = t >> 3;              // row group 0..31
    const int chunk = q * QCH + c;     // chunk within full row 0..31

    const f32x4* feat4 = reinterpret_cast<const f32x4*>(feat);
    f32x4* out4 = reinterpret_cast<f32x4*>(out);

    // ---- pass 1a: bulk load into registers (static indices) ----
    f32x4 buf[MAXK];
    #pragma unroll
    for (int k = 0; k < MAXK; ++k) {
        const int r = start + g + k * RG;
        if (r < end) buf[k] = feat4[r * CPRF + chunk];
    }

    // ---- pass 1b: accumulate sum / sumsq from registers ----
    f32x4 s0 = 0.f, q0 = 0.f;
    #pragma unroll
    for (int k = 0; k < MAXK; ++k) {
        const int r = start + g + k * RG;
        if (r < end) {
            s0 += buf[k];
            q0 += buf[k] * buf[k];
        }
    }

    // tail rows beyond the register window (rare)
    const int tail_base = start + g + MAXK * RG;
    for (int r = tail_base; r < end; r += RG) {
        f32x4 v = feat4[r * CPRF + chunk];
        s0 += v;
        q0 += v * v;
    }

    // reduce across the 8 row-groups sharing chunk c within this wave
    #pragma unroll
    for (int i = 0; i < 4; ++i) {
        s0[i] += __shfl_xor(s0[i], 8);
        s0[i] += __shfl_xor(s0[i], 16);
        s0[i] += __shfl_xor(s0[i], 32);
        q0[i] += __shfl_xor(q0[i], 8);
        q0[i] += __shfl_xor(q0[i], 16);
        q0[i] += __shfl_xor(q0[i], 32);
    }

    const int w    = t >> 6;   // wave id 0..3
    const int lane = t & 63;
    if (lane < QCH) {
        s_sum[w][lane] = s0;
        s_sq[w][lane]  = q0;
    }
    __syncthreads();

    // ---- per-column affine coefficients (threads 0..7) ----
    if (t < QCH) {
        f32x4 sm = s_sum[0][t];
        f32x4 sg = s_sq[0][t];
        #pragma unroll
        for (int i = 1; i < WAVES; ++i) {
            sm += s_sum[i][t];
            sg += s_sq[i][t];
        }
        const float cnt = (float)max(end - start, 1);
        const float inv = 1.0f / cnt;
        const int wc = q * QCH + t;
        const f32x4 wv  = reinterpret_cast<const f32x4*>(weight)[wc];
        const f32x4 bi  = reinterpret_cast<const f32x4*>(bias)[wc];
        const f32x4 msc = reinterpret_cast<const f32x4*>(mean_scale)[wc];
        f32x4 A, B;
        #pragma unroll
        for (int i = 0; i < 4; ++i) {
            float mean = sm[i] * inv;
            float ms   = mean * msc[i];
            float var  = fmaxf(sg[i] * inv - 2.f * mean * ms + ms * ms, 0.f);
            float istd = rsqrtf(var + EPSV);
            A[i] = wv[i] * istd;
            B[i] = bi[i] - A[i] * ms;
        }
        s_a[t] = A;
        s_b[t] = B;
    }
    __syncthreads();

    // ---- pass 2: apply from registers, zero re-loads, nontemporal stores ----
    const f32x4 A = s_a[c];
    const f32x4 B = s_b[c];

    #pragma unroll
    for (int k = 0; k < MAXK; ++k) {
        const int r = start + g + k * RG;
        if (r < end)
            __builtin_nontemporal_store(A * buf[k] + B, &out4[r * CPRF + chunk]);
    }
    // tail rows: re-read via L2/L3
    for (int r = tail_base; r < end; r += RG) {
        f32x4 v = feat4[r * CPRF + chunk];
        __builtin_nontemporal_store(A * v + B, &out4[r * CPRF + chunk]);
    }
}

extern "C" void kernel_launch(void* const* d_in, const int* in_sizes, int n_in,
                              void* d_out, int out_size, void* d_ws, size_t ws_size,
                              hipStream_t stream) {
    const float* feat       = (const float*)d_in[0];
    const int*   seg        = (const int*)d_in[1];
    const float* weight     = (const float*)d_in[2];
    const float* bias       = (const float*)d_in[3];
    const float* mean_scale = (const float*)d_in[4];
    float* out = (float*)d_out;

    const int N = in_sizes[0] / D;   // 1,000,000

    graphnorm_fused<<<NSEG * 4, BLOCK, 0, stream>>>(
        feat, seg, weight, bias, mean_scale, out, N);
}